// Round 18
// baseline (235.339 us; speedup 1.0000x reference)
//
#include <hip/hip_runtime.h>
#include <hip/hip_bf16.h>

// Joiner: logits[n,t,u,v] = sum_d tanh(enc[n,t,d]+dec[n,u,d]) * W[v,d] + b[v]
// N=8 T=200 U=100 D=512 V=500  -> GEMM M=160000, K=512, N=500 (padded 512)
//
// R15: A-RESIDENT MULTI-PASS. BM=32, 256thr. Stage full 32x512 tanh-A ONCE
// into 32KB swizzled LDS (1 barrier), then 2 BARRIER-FREE passes over V
// (cols 0-255 / 256-511): wave owns 32x64, acc[2][4]=16 regs, B 3-deep
// in-place prefetch (dist-3 steps), aF dbuf. ~110 regs <= 128 ->
// launch_bounds(256,4) -> 4 waves/SIMD; LDS 40960B -> 4 blocks/CU ->
// 16 waves/CU (2.5x R10's occupancy), ZERO tanh redundancy. Cost: B L2
// traffic 2.56GB (2x R10). Streamed 8-row-chunk epilogue, raw lgkm bars.

#define NB 8
#define TT 200
#define UU 100
#define DD 512
#define VV 500
#define VP 512
#define BM 32
#define BK 32
#define THREADS 256
#define MROWS (NB*TT*UU)   // 160000
#define MBLOCKS (MROWS/BM) // 5000

typedef __attribute__((ext_vector_type(4))) float         f32x4;
typedef __attribute__((ext_vector_type(8))) short         s16x8;
typedef __attribute__((ext_vector_type(4))) unsigned int  u32x4;

#define RAW_BAR() do { asm volatile("s_waitcnt lgkmcnt(0)" ::: "memory"); \
                       __builtin_amdgcn_s_barrier(); } while (0)

__device__ __forceinline__ unsigned short f2bf(float f) {
    unsigned int u = __builtin_bit_cast(unsigned int, f);
    u = (u + 0x7FFFu + ((u >> 16) & 1u)) >> 16;   // round-to-nearest-even
    return (unsigned short)u;
}

__device__ __forceinline__ unsigned int cvt_pk_bf16(float a, float b) {
    unsigned int r;
    asm("v_cvt_pk_bf16_f32 %0, %1, %2" : "=v"(r) : "v"(a), "v"(b));
    return r;
}

__device__ __forceinline__ float fast_tanh(float x) {
    float e = __builtin_amdgcn_exp2f(x * 2.88539008177793f);
    return __builtin_fmaf(-2.0f, __builtin_amdgcn_rcpf(e + 1.0f), 1.0f);
}

// ---- prep: W (500x512 f32) -> bf16, padded to 512 rows, tiled [kc][v][32] ----
__global__ void prep_w(const float* __restrict__ W, unsigned short* __restrict__ Wt) {
    int idx = blockIdx.x * 256 + threadIdx.x;   // 0 .. 512*512-1
    int k = idx & 511;
    int v = idx >> 9;
    float val = (v < VV) ? W[v * DD + k] : 0.0f;
    Wt[(k >> 5) * (VP * BK) + v * BK + (k & 31)] = f2bf(val);
}

// One K-step of a pass. AFC holds A[kc] frags, BC_ holds B[kc] frags.
// Issues aFn for kc+1 (LDS) and reloads BC_ with B[kc+3] (global, in-place
// after last use -> ~3-step in-flight window, no barriers anywhere).
#define KSTEP(kc, BC_, AFC_, AFN_)                                            \
  {                                                                           \
    if ((kc) < 15) {                                                          \
      _Pragma("unroll")                                                       \
      for (int m = 0; m < 2; ++m) {                                           \
        int row = m * 16 + lr;                                                \
        int swz = ((((kc)+1) * 4 + lk) ^ (lr & 7));                           \
        AFN_[m] = *(const s16x8*)(&lA[row * 512 + swz * 8]);                  \
      }                                                                       \
    }                                                                         \
    _Pragma("unroll")                                                         \
    for (int f = 0; f < 4; ++f) {                                             \
      acc[0][f] = __builtin_amdgcn_mfma_f32_16x16x32_bf16(AFC_[0], BC_[f],    \
                                                          acc[0][f], 0,0,0);  \
      acc[1][f] = __builtin_amdgcn_mfma_f32_16x16x32_bf16(AFC_[1], BC_[f],    \
                                                          acc[1][f], 0,0,0);  \
      if ((kc) <= 12)                                                         \
        BC_[f] = *(const s16x8*)(wptrP + ((kc)+3) * (VP * BK) + f * (16*BK)); \
    }                                                                         \
  }

__global__ __launch_bounds__(THREADS, 4) void joiner_kernel(
    const float* __restrict__ enc, const float* __restrict__ dec,
    const unsigned short* __restrict__ Wt, const float* __restrict__ bias,
    float* __restrict__ out)
{
    // A tile 32x512 bf16 swizzled (32768 B) + epilogue chunk 8x256 f32 (8192 B)
    __shared__ __align__(16) char smem[40960];
    unsigned short* lA = (unsigned short*)smem;
    float* lchunk = (float*)(smem + 32768);

    const int tid  = threadIdx.x;
    const int mb   = blockIdx.x;
    const int lane = tid & 63;
    const int wn   = tid >> 6;       // 0..3: 64-col slab within the pass
    const int lr   = lane & 15;
    const int lk   = lane >> 4;

    // ---- stage A once: thread owns row srow, cols [scol0, scol0+64) ----
    const int srow  = tid >> 3;          // 0..31
    const int scol0 = (tid & 7) << 6;    // 0,64,...,448

    {
        int r   = mb * BM + srow;
        int n   = r / (TT * UU);
        int rem = r - n * (TT * UU);
        int t   = rem / UU;
        int u   = rem - t * UU;
        const float* ep = enc + (n * TT + t) * DD + scol0;
        const float* dp = dec + (n * UU + u) * DD + scol0;
        #pragma unroll
        for (int c8 = 0; c8 < 8; ++c8) {
            f32x4 e0 = *(const f32x4*)(ep + c8 * 8);
            f32x4 e1 = *(const f32x4*)(ep + c8 * 8 + 4);
            f32x4 d0 = *(const f32x4*)(dp + c8 * 8);
            f32x4 d1 = *(const f32x4*)(dp + c8 * 8 + 4);
            u32x4 wds;
            wds[0] = cvt_pk_bf16(fast_tanh(e0[0]+d0[0]), fast_tanh(e0[1]+d0[1]));
            wds[1] = cvt_pk_bf16(fast_tanh(e0[2]+d0[2]), fast_tanh(e0[3]+d0[3]));
            wds[2] = cvt_pk_bf16(fast_tanh(e1[0]+d1[0]), fast_tanh(e1[1]+d1[1]));
            wds[3] = cvt_pk_bf16(fast_tanh(e1[2]+d1[2]), fast_tanh(e1[3]+d1[3]));
            int slot = (scol0 >> 3) + c8;            // 0..63
            int swz  = slot ^ (srow & 7);
            *(u32x4*)(&lA[srow * 512 + swz * 8]) = wds;
        }
    }
    RAW_BAR();   // A visible to all waves; the ONLY pre-epilogue barrier

    float* outrow = out + (long)mb * BM * VV;

    #pragma unroll
    for (int p = 0; p < 2; ++p) {
        // per-pass B pointer: v = p*256 + wn*64 + f*16 + lr, k = lk*8
        const unsigned short* wptrP = Wt + (p * 256 + wn * 64 + lr) * BK + lk * 8;

        f32x4 acc[2][4];
        #pragma unroll
        for (int m = 0; m < 2; ++m)
            #pragma unroll
            for (int f = 0; f < 4; ++f)
                acc[m][f] = (f32x4){0.f, 0.f, 0.f, 0.f};

        // B prologue: 3 steps deep
        s16x8 b0[4], b1[4], b2[4];
        #pragma unroll
        for (int f = 0; f < 4; ++f) {
            b0[f] = *(const s16x8*)(wptrP + 0 * (VP * BK) + f * (16 * BK));
            b1[f] = *(const s16x8*)(wptrP + 1 * (VP * BK) + f * (16 * BK));
            b2[f] = *(const s16x8*)(wptrP + 2 * (VP * BK) + f * (16 * BK));
        }
        // aF prologue (kc=0)
        s16x8 af0[2], af1[2];
        #pragma unroll
        for (int m = 0; m < 2; ++m) {
            int row = m * 16 + lr;
            int swz = (lk ^ (lr & 7));
            af0[m] = *(const s16x8*)(&lA[row * 512 + swz * 8]);
        }

        // ---- 16 barrier-free K-steps ----
        KSTEP(0,  b0, af0, af1)
        KSTEP(1,  b1, af1, af0)
        KSTEP(2,  b2, af0, af1)
        KSTEP(3,  b0, af1, af0)
        KSTEP(4,  b1, af0, af1)
        KSTEP(5,  b2, af1, af0)
        KSTEP(6,  b0, af0, af1)
        KSTEP(7,  b1, af1, af0)
        KSTEP(8,  b2, af0, af1)
        KSTEP(9,  b0, af1, af0)
        KSTEP(10, b1, af0, af1)
        KSTEP(11, b2, af1, af0)
        KSTEP(12, b0, af0, af1)
        KSTEP(13, b1, af1, af0)
        KSTEP(14, b2, af0, af1)
        KSTEP(15, b0, af1, af0)

        // ---- pass epilogue: 4 chunks of 8 rows x 256 cols ----
        float bv[4];
        #pragma unroll
        for (int f = 0; f < 4; ++f) {
            int v = p * 256 + wn * 64 + f * 16 + lr;
            bv[f] = (v < VV) ? bias[v] : 0.0f;
        }
        const int segmax = (p == 0) ? 64 : 61;   // 256 or 244 cols / 4
        float* outcol = outrow + p * 256;

        for (int ch = 0; ch < 4; ++ch) {
            RAW_BAR();   // previous chunk's reads done (or K-loop desync sync)
            if ((lk >> 1) == (ch & 1)) {
                int m = ch >> 1;
                #pragma unroll
                for (int f = 0; f < 4; ++f) {
                    int vloc = wn * 64 + f * 16 + lr;
                    #pragma unroll
                    for (int q = 0; q < 4; ++q)
                        lchunk[((lk & 1) * 4 + q) * 256 + vloc] = acc[m][f][q] + bv[f];
                }
            }
            RAW_BAR();   // chunk visible
            #pragma unroll
            for (int i = 0; i < 2; ++i) {
                int idx = i * THREADS + tid;     // 0..511
                int row = idx >> 6;              // 0..7
                int seg = idx & 63;
                if (seg < segmax)
                    *(f32x4*)(outcol + (long)(ch * 8 + row) * VV + seg * 4) =
                        *(const f32x4*)(lchunk + row * 256 + seg * 4);
            }
        }
    }
}

extern "C" void kernel_launch(void* const* d_in, const int* in_sizes, int n_in,
                              void* d_out, int out_size, void* d_ws, size_t ws_size,
                              hipStream_t stream) {
    const float* enc = (const float*)d_in[0];
    const float* dec = (const float*)d_in[1];
    const float* W   = (const float*)d_in[2];
    const float* b   = (const float*)d_in[3];
    float* out = (float*)d_out;
    unsigned short* Wt = (unsigned short*)d_ws;   // 512*512*2 = 512 KB

    prep_w<<<dim3((VP * DD) / 256), dim3(256), 0, stream>>>(W, Wt);
    joiner_kernel<<<dim3(MBLOCKS), dim3(THREADS), 0, stream>>>(enc, dec, Wt, b, out);
}

// Round 19
// 131.379 us; speedup vs baseline: 1.7913x; 1.7913x over previous
//
#include <hip/hip_runtime.h>
#include <hip/hip_bf16.h>

// Joiner: logits[n,t,u,v] = sum_d tanh(enc[n,t,d]+dec[n,u,d]) * W[v,d] + b[v]
// N=8 T=200 U=100 D=512 V=500  -> GEMM M=160000, K=512, N=500 (padded 512)
//
// R16 = R10 (best, 130.6us) restored + e/d(kc+2) loads hoisted above the
// tanh staging (earlier issue, land under MFMA cluster). R10 structure:
// BM=64 BN=512 256thr, counted-vmcnt cross-barrier B reg-dbuf prefetch (T4)
// with raw {lgkmcnt(0); s_barrier} barriers, tanh-staged dbuf-LDS A
// (1 barrier/K-step), streamed 16-row LDS epilogue (ideal WRITE_SIZE).
// R14/R15 established: BM=64 + 2 blocks/CU is the constrained optimum
// (BM>=128 loses epilogue/latency overlap; BM<=32 doubles B-L2 pressure;
// occupancy>2 waves/SIMD verified non-binding by R15's 44% occ / 13.7% mfma).

#define NB 8
#define TT 200
#define UU 100
#define DD 512
#define VV 500
#define VP 512
#define BM 64
#define BK 32
#define KSTEPS 16          // 512/32
#define THREADS 256
#define LDA 40             // BK + 8 pad (ushort units, 80B row stride)
#define MROWS (NB*TT*UU)   // 160000
#define MBLOCKS (MROWS/BM) // 2500

typedef __attribute__((ext_vector_type(4))) float         f32x4;
typedef __attribute__((ext_vector_type(8))) short         s16x8;
typedef __attribute__((ext_vector_type(4))) unsigned int  u32x4;

#define RAW_BAR() do { asm volatile("s_waitcnt lgkmcnt(0)" ::: "memory"); \
                       __builtin_amdgcn_s_barrier(); } while (0)

__device__ __forceinline__ unsigned short f2bf(float f) {
    unsigned int u = __builtin_bit_cast(unsigned int, f);
    u = (u + 0x7FFFu + ((u >> 16) & 1u)) >> 16;   // round-to-nearest-even
    return (unsigned short)u;
}

// pack 2 f32 -> 2 bf16 (RNE) in one instruction
__device__ __forceinline__ unsigned int cvt_pk_bf16(float a, float b) {
    unsigned int r;
    asm("v_cvt_pk_bf16_f32 %0, %1, %2" : "=v"(r) : "v"(a), "v"(b));
    return r;
}

__device__ __forceinline__ float fast_tanh(float x) {
    // tanh(x) = 1 - 2/(1+2^(2x*log2e)); saturations via exp inf/0
    float e = __builtin_amdgcn_exp2f(x * 2.88539008177793f);
    return __builtin_fmaf(-2.0f, __builtin_amdgcn_rcpf(e + 1.0f), 1.0f);
}

// ---- prep: W (500x512 f32) -> bf16, padded to 512 rows, tiled [kc][v][32] ----
__global__ void prep_w(const float* __restrict__ W, unsigned short* __restrict__ Wt) {
    int idx = blockIdx.x * 256 + threadIdx.x;   // 0 .. 512*512-1
    int k = idx & 511;
    int v = idx >> 9;
    float val = (v < VV) ? W[v * DD + k] : 0.0f;
    Wt[(k >> 5) * (VP * BK) + v * BK + (k & 31)] = f2bf(val);
}

// One K-step. At entry: CUR holds A[kc] (barrier passed), BC holds B[kc]
// (loads in flight, counted-vmcnt at consume), e/d regs hold enc/dec[kc+1].
#define KBODY(kc, CUR, NXT, BC, BNX)                                          \
  {                                                                           \
    /* issue next step's B fragments (stay in flight across the barrier) */   \
    if ((kc) < KSTEPS - 1) {                                                  \
      _Pragma("unroll")                                                       \
      for (int f = 0; f < 8; ++f)                                             \
        BNX[f] = *(const s16x8*)(wptr + ((kc)+1) * (VP * BK) + f * (16*BK));  \
    }                                                                         \
    /* issue e/d loads for kc+2 EARLY (hoisted; land under MFMA) */           \
    f32x4 ne0, ne1, nd0, nd1;                                                 \
    if ((kc) < KSTEPS - 2) {                                                  \
      const float* e2 = ep + ((kc)+2) * BK;                                   \
      const float* d2 = dp + ((kc)+2) * BK;                                   \
      ne0 = *(const f32x4*)(e2);  ne1 = *(const f32x4*)(e2 + 4);              \
      nd0 = *(const f32x4*)(d2);  nd1 = *(const f32x4*)(d2 + 4);              \
    }                                                                         \
    /* A fragments for this step */                                           \
    s16x8 aF[4];                                                              \
    _Pragma("unroll")                                                         \
    for (int m = 0; m < 4; ++m)                                               \
      aF[m] = *(const s16x8*)(&CUR[(m * 16 + lr) * LDA + lk * 8]);            \
    /* stage A[kc+1] from e/d regs */                                         \
    if ((kc) < KSTEPS - 1) {                                                  \
      u32x4 wds;                                                              \
      wds[0] = cvt_pk_bf16(fast_tanh(e0[0]+d0[0]), fast_tanh(e0[1]+d0[1]));   \
      wds[1] = cvt_pk_bf16(fast_tanh(e0[2]+d0[2]), fast_tanh(e0[3]+d0[3]));   \
      wds[2] = cvt_pk_bf16(fast_tanh(e1[0]+d1[0]), fast_tanh(e1[1]+d1[1]));   \
      wds[3] = cvt_pk_bf16(fast_tanh(e1[2]+d1[2]), fast_tanh(e1[3]+d1[3]));   \
      *(u32x4*)(&NXT[srow * LDA + sk]) = wds;                                 \
    }                                                                         \
    /* rotate e/d regs */                                                     \
    if ((kc) < KSTEPS - 2) {                                                  \
      e0 = ne0; e1 = ne1; d0 = nd0; d1 = nd1;                                 \
    }                                                                         \
    /* 32 MFMAs on BC (counted vmcnt at consume, not 0) */                    \
    __builtin_amdgcn_s_setprio(1);                                            \
    _Pragma("unroll")                                                         \
    for (int m = 0; m < 4; ++m)                                               \
      _Pragma("unroll")                                                       \
      for (int f = 0; f < 8; ++f)                                             \
        acc[m][f] = __builtin_amdgcn_mfma_f32_16x16x32_bf16(aF[m], BC[f],     \
                                                            acc[m][f],0,0,0); \
    __builtin_amdgcn_s_setprio(0);                                            \
    /* raw barrier: drain LDS only, keep global loads in flight */            \
    if ((kc) < KSTEPS - 1) RAW_BAR();                                         \
  }

__global__ __launch_bounds__(THREADS, 2) void joiner_kernel(
    const float* __restrict__ enc, const float* __restrict__ dec,
    const unsigned short* __restrict__ Wt, const float* __restrict__ bias,
    float* __restrict__ out)
{
    // union: K-loop A dbuf (2 x 5120 B) / epilogue chunk 16x500 f32 (32000 B)
    __shared__ __align__(16) char smem[32000];
    unsigned short* lA0 = (unsigned short*)smem;
    unsigned short* lA1 = (unsigned short*)(smem + BM * LDA * 2);

    const int tid  = threadIdx.x;
    const int mb   = blockIdx.x;
    const int lane = tid & 63;
    const int wn   = tid >> 6;       // 0..3: 128-col quarter
    const int lr   = lane & 15;
    const int lk   = lane >> 4;

    // staging: each thread produces 8 activations of one row
    const int srow = tid >> 2;          // 0..63
    const int sk   = (tid & 3) << 3;    // 0,8,16,24

    int r   = mb * BM + srow;
    int n   = r / (TT * UU);
    int rem = r - n * (TT * UU);
    int t   = rem / UU;
    int u   = rem - t * UU;
    const float* ep = enc + (n * TT + t) * DD + sk;
    const float* dp = dec + (n * UU + u) * DD + sk;

    // per-thread B pointer into pre-tiled Wt: v = wn*128 + f*16 + lr, k = lk*8
    const unsigned short* wptr = Wt + (wn * 128 + lr) * BK + lk * 8;

    f32x4 e0, e1, d0, d1;
    s16x8 b0[8], b1[8];

    // ---- prologue: e/d[0], issue B[0], stage A[0], e/d[1], raw barrier ----
    e0 = *(const f32x4*)(ep);     e1 = *(const f32x4*)(ep + 4);
    d0 = *(const f32x4*)(dp);     d1 = *(const f32x4*)(dp + 4);
    #pragma unroll
    for (int f = 0; f < 8; ++f)
        b0[f] = *(const s16x8*)(wptr + f * (16 * BK));
    {
        u32x4 wds;
        wds[0] = cvt_pk_bf16(fast_tanh(e0[0]+d0[0]), fast_tanh(e0[1]+d0[1]));
        wds[1] = cvt_pk_bf16(fast_tanh(e0[2]+d0[2]), fast_tanh(e0[3]+d0[3]));
        wds[2] = cvt_pk_bf16(fast_tanh(e1[0]+d1[0]), fast_tanh(e1[1]+d1[1]));
        wds[3] = cvt_pk_bf16(fast_tanh(e1[2]+d1[2]), fast_tanh(e1[3]+d1[3]));
        *(u32x4*)(&lA0[srow * LDA + sk]) = wds;
    }
    e0 = *(const f32x4*)(ep + BK);     e1 = *(const f32x4*)(ep + BK + 4);
    d0 = *(const f32x4*)(dp + BK);     d1 = *(const f32x4*)(dp + BK + 4);
    RAW_BAR();

    f32x4 acc[4][8];
    #pragma unroll
    for (int m = 0; m < 4; ++m)
        #pragma unroll
        for (int f = 0; f < 8; ++f)
            acc[m][f] = (f32x4){0.f, 0.f, 0.f, 0.f};

    // ---- K-loop: 8 x 2 bodies; B reg-dbuf b0/b1, A LDS-dbuf lA0/lA1 ----
    #pragma unroll
    for (int kk = 0; kk < KSTEPS; kk += 2) {
        KBODY(kk,     lA0, lA1, b0, b1)
        KBODY(kk + 1, lA1, lA0, b1, b0)
    }

    // ---- epilogue: acc -> LDS 16-row chunks -> streaming f32x4 stores ----
    float bv[8];
    #pragma unroll
    for (int f = 0; f < 8; ++f) {
        int v = wn * 128 + f * 16 + lr;
        bv[f] = (v < VV) ? bias[v] : 0.0f;
    }

    float* lchunk = (float*)smem;                 // 16*500 f32 = 32000 B
    float* outbase = out + (long)mb * BM * VV;

    for (int m = 0; m < 4; ++m) {
        RAW_BAR();   // K-loop LDS reads done / previous chunk streamed
        #pragma unroll
        for (int f = 0; f < 8; ++f) {
            int v = wn * 128 + f * 16 + lr;
            if (v < VV) {
                #pragma unroll
                for (int q = 0; q < 4; ++q)
                    lchunk[(lk * 4 + q) * VV + v] = acc[m][f][q] + bv[f];
            }
        }
        RAW_BAR();   // chunk writes visible
        // 16 rows x 500 f32 = 8000 contiguous floats = 2000 f32x4
        float* dst = outbase + m * 16 * VV;
        #pragma unroll
        for (int i = 0; i < 8; ++i) {
            int c = i * THREADS + tid;
            if (c < 2000)
                *(f32x4*)(dst + c * 4) = *(const f32x4*)(lchunk + c * 4);
        }
    }
}

extern "C" void kernel_launch(void* const* d_in, const int* in_sizes, int n_in,
                              void* d_out, int out_size, void* d_ws, size_t ws_size,
                              hipStream_t stream) {
    const float* enc = (const float*)d_in[0];
    const float* dec = (const float*)d_in[1];
    const float* W   = (const float*)d_in[2];
    const float* b   = (const float*)d_in[3];
    float* out = (float*)d_out;
    unsigned short* Wt = (unsigned short*)d_ws;   // 512*512*2 = 512 KB

    prep_w<<<dim3((VP * DD) / 256), dim3(256), 0, stream>>>(W, Wt);
    joiner_kernel<<<dim3(MBLOCKS), dim3(THREADS), 0, stream>>>(enc, dec, Wt, b, out);
}